// Round 15
// baseline (430.503 us; speedup 1.0000x reference)
//
#include <hip/hip_runtime.h>

#define BN_EPS 1e-5

// ---------------- adder conv 3x3 pad1, split-K partial -> plain stores to P[z] ----------------
// block: 256 threads = 16 pixel-threads (tx) x 16 o-threads (ty); each thread: TO o x TP pixels
// Inner accumulate: exactly 2 VALU/element via inline asm (R14-proven: VGPR 52, -15%).
// CPR==8 layers (L4,L6) stage weights in TWO phases of 4 channels: LDS 38.4->19.5KB
// -> 8 blocks/CU (LDS was the occupancy binder at 4 blocks/CU; VGPR headroom is 52->128).
template<int TP, int TO, int CPR>
__global__ __launch_bounds__(256) void adder_partial(
    const float* __restrict__ x, const float* __restrict__ w,
    float* __restrict__ P, int C, int H, int W, int O)
{
    constexpr int OT = 16 * TO;          // o-tile per block
    constexpr int PADOT = OT + 4;
    constexpr int PHASES = (CPR == 8) ? 2 : 1;
    constexpr int CPP = CPR / PHASES;    // channels staged per phase
    constexpr int NKH = CPP * 9;
    constexpr int NITEMS = NKH * OT;
    constexpr int ITERS = (NITEMS + 255) / 256;
    constexpr int BATCH = (ITERS < 8) ? ITERS : 8;
    __shared__ float w_s[NKH][PADOT];

    const int tid = threadIdx.x;
    const int tx = tid & 15, ty = tid >> 4;
    const int o_blk = blockIdx.y * OT;
    const int tpr = W / TP;              // tiles per row (exact: W%TP==0 for all layer configs)
    const int PT = 2 * H * tpr;          // B=2
    const int pt = blockIdx.x * 16 + tx;
    const bool act = pt < PT;
    int b = 0, y = 0, x0 = 0;
    if (act) { int t = pt; x0 = (t % tpr) * TP; t /= tpr; y = t % H; b = t / H; }
    const int c0 = blockIdx.z * CPR;

    bool rv[3]; int yoff[3];
#pragma unroll
    for (int dy = 0; dy < 3; ++dy) {
        int yy = y + dy - 1;
        bool v = act && (yy >= 0) && (yy < H);
        rv[dy] = v; yoff[dy] = (v ? yy : 0) * W;
    }
    const bool lok = (x0 > 0), rok = (x0 + TP) < W;
    const int off0 = lok ? -1 : 0;
    const int offT = rok ? TP : (TP - 1);

    float acc[TO][TP] = {};
    const int c9 = C * 9;

    for (int ph = 0; ph < PHASES; ++ph) {
        const int cbase = c0 + ph * CPP;
        if (ph) __syncthreads();         // WAR: finish compute on phase-0 weights before restage

        // ---- staging: fully unrolled, batched loads (8 in flight), then batched LDS writes ----
        const float* wbase = w + ((size_t)o_blk * C + cbase) * 9;   // + ol*C*9 + kk
#pragma unroll
        for (int g0 = 0; g0 < ITERS; g0 += BATCH) {
            float tmp[BATCH];
#pragma unroll
            for (int u = 0; u < BATCH; ++u) {
                int it = g0 + u;
                if (it < ITERS) {
                    int idx = tid + it * 256;
                    int ol = idx / NKH, kk = idx - ol * NKH;
                    if (idx < NITEMS) tmp[u] = wbase[(size_t)ol * c9 + kk];
                }
            }
#pragma unroll
            for (int u = 0; u < BATCH; ++u) {
                int it = g0 + u;
                if (it < ITERS) {
                    int idx = tid + it * 256;
                    int ol = idx / NKH, kk = idx - ol * NKH;
                    if (idx < NITEMS) w_s[kk][ol] = tmp[u];
                }
            }
        }
        __syncthreads();

        for (int cc = 0; cc < CPP; ++cc) {
            const float* xc = x + ((size_t)(b * C + cbase + cc)) * H * W;
#pragma unroll
            for (int dy = 0; dy < 3; ++dy) {
                const float* rp = xc + yoff[dy] + x0;
                float xr[TP + 2];
                if constexpr (TP == 4) {
                    float4 v = *(const float4*)rp;          // 16B-aligned: W%4==0, x0%4==0
                    xr[1] = rv[dy] ? v.x : 0.f;
                    xr[2] = rv[dy] ? v.y : 0.f;
                    xr[3] = rv[dy] ? v.z : 0.f;
                    xr[4] = rv[dy] ? v.w : 0.f;
                    float vl = rp[off0]; xr[0]      = (rv[dy] && lok) ? vl : 0.f;
                    float vr = rp[offT]; xr[TP + 1] = (rv[dy] && rok) ? vr : 0.f;
                } else {                                     // TP == 6: x0%2==0 -> 8B-aligned rows
                    float2 a0 = *(const float2*)rp;
                    float2 a1 = *(const float2*)(rp + 2);
                    float2 a2 = *(const float2*)(rp + 4);
                    xr[1] = rv[dy] ? a0.x : 0.f;
                    xr[2] = rv[dy] ? a0.y : 0.f;
                    xr[3] = rv[dy] ? a1.x : 0.f;
                    xr[4] = rv[dy] ? a1.y : 0.f;
                    xr[5] = rv[dy] ? a2.x : 0.f;
                    xr[6] = rv[dy] ? a2.y : 0.f;
                    float vl = rp[off0]; xr[0]      = (rv[dy] && lok) ? vl : 0.f;
                    float vr = rp[offT]; xr[TP + 1] = (rv[dy] && rok) ? vr : 0.f;
                }
#pragma unroll
                for (int dx = 0; dx < 3; ++dx) {
                    const float* wrow = &w_s[cc * 9 + dy * 3 + dx][ty * TO];
                    float wv[TO];
                    if constexpr (TO == 8) {
                        float4 wa = *(const float4*)wrow;
                        float4 wb = *(const float4*)(wrow + 4);
                        wv[0]=wa.x; wv[1]=wa.y; wv[2]=wa.z; wv[3]=wa.w;
                        wv[4]=wb.x; wv[5]=wb.y; wv[6]=wb.z; wv[7]=wb.w;
                    } else if constexpr (TO == 4) {
                        float4 wa = *(const float4*)wrow;
                        wv[0]=wa.x; wv[1]=wa.y; wv[2]=wa.z; wv[3]=wa.w;
                    } else {                                 // TO == 2
                        float2 wa = *(const float2*)wrow;
                        wv[0]=wa.x; wv[1]=wa.y;
                    }
#pragma unroll
                    for (int i = 0; i < TO; i++)
#pragma unroll
                        for (int p = 0; p < TP; p++) {
                            float d;
                            // exactly 2 VALU: d = x - w; acc += |d| (abs as VOP3 src modifier)
                            asm("v_sub_f32 %1, %2, %3\n\t"
                                "v_add_f32_e64 %0, %0, |%1|"
                                : "+v"(acc[i][p]), "=&v"(d)
                                : "v"(xr[p + dx]), "v"(wv[i]));
                        }
                }
            }
        }
    }

    if (act) {
        float* Pz = P + (size_t)blockIdx.z * ((size_t)2 * O * H * W);
        const int o0 = o_blk + ty * TO;
#pragma unroll
        for (int i = 0; i < TO; i++) {
            float* Tp = Pz + ((size_t)(b * O + (o0 + i)) * H + y) * W + x0;
            if constexpr (TP == 4) {
                *(float4*)Tp = make_float4(-acc[i][0], -acc[i][1], -acc[i][2], -acc[i][3]);
            } else {
                *(float2*)Tp       = make_float2(-acc[i][0], -acc[i][1]);
                *(float2*)(Tp + 2) = make_float2(-acc[i][2], -acc[i][3]);
                *(float2*)(Tp + 4) = make_float2(-acc[i][4], -acc[i][5]);
            }
        }
    }
}

// ---------------- z-reduce P -> T, fused BN sum/sumsq (2 double atomics per block) ----------------
__global__ __launch_bounds__(256) void reduce_stats(
    const float* __restrict__ P, float* __restrict__ T, double* __restrict__ dsum,
    int O, int HW, int RS)
{
    __shared__ double sh1[256];
    __shared__ double sh2[256];
    const int bc = blockIdx.x;          // b*O + c
    const int c = bc % O;
    const int n4 = HW >> 2;             // HW % 4 == 0 for all layers
    const size_t outsz4 = (size_t)2 * O * n4;
    const float4* P4 = (const float4*)P + (size_t)bc * n4;
    float4* T4 = (float4*)T + (size_t)bc * n4;
    double a = 0.0, q = 0.0;
    for (int i4 = threadIdx.x; i4 < n4; i4 += 256) {
        float4 s0 = make_float4(0.f, 0.f, 0.f, 0.f);
        float4 s1 = make_float4(0.f, 0.f, 0.f, 0.f);
        int z = 0;
        for (; z + 1 < RS; z += 2) {
            float4 v0 = P4[(size_t)z * outsz4 + i4];
            float4 v1 = P4[(size_t)(z + 1) * outsz4 + i4];
            s0.x += v0.x; s0.y += v0.y; s0.z += v0.z; s0.w += v0.w;
            s1.x += v1.x; s1.y += v1.y; s1.z += v1.z; s1.w += v1.w;
        }
        if (z < RS) {
            float4 v = P4[(size_t)z * outsz4 + i4];
            s0.x += v.x; s0.y += v.y; s0.z += v.z; s0.w += v.w;
        }
        s0.x += s1.x; s0.y += s1.y; s0.z += s1.z; s0.w += s1.w;
        T4[i4] = s0;
        a += (double)s0.x + (double)s0.y + (double)s0.z + (double)s0.w;
        q += (double)s0.x * s0.x + (double)s0.y * s0.y
           + (double)s0.z * s0.z + (double)s0.w * s0.w;
    }
    sh1[threadIdx.x] = a; sh2[threadIdx.x] = q;
    __syncthreads();
    for (int s = 128; s > 0; s >>= 1) {
        if (threadIdx.x < s) { sh1[threadIdx.x] += sh1[threadIdx.x + s]; sh2[threadIdx.x] += sh2[threadIdx.x + s]; }
        __syncthreads();
    }
    if (threadIdx.x == 0) {
        unsafeAtomicAdd(&dsum[2 * c],     sh1[0]);
        unsafeAtomicAdd(&dsum[2 * c + 1], sh2[0]);
    }
}

__device__ __forceinline__ void bn_coef(const double* __restrict__ dsum,
                                        const float* __restrict__ g,
                                        const float* __restrict__ beta,
                                        int c, int HW, float& sc, float& sh)
{
    double n = 2.0 * (double)HW;
    double mu = dsum[2 * c] / n;
    double var = dsum[2 * c + 1] / n - mu * mu;
    double inv = 1.0 / sqrt(var + (double)BN_EPS);
    double s = (double)g[c] * inv;
    sc = (float)s;
    sh = (float)((double)beta[c] - mu * s);
}

// ---------------- BN apply (inline coef) + feature write + maxpool2 + relu ----------------
__global__ __launch_bounds__(256) void bn_apply_pool(
    const float* __restrict__ T, const double* __restrict__ dsum,
    const float* __restrict__ g, const float* __restrict__ beta,
    float* __restrict__ feat, float* __restrict__ A, int C, int H, int W, int total)
{
    int idx = blockIdx.x * 256 + threadIdx.x;
    if (idx >= total) return;
    int Wh = W >> 1, Hh = H >> 1;
    int px = idx % Wh; int t = idx / Wh;
    int py = t % Hh; t /= Hh;
    int c = t % C; int b = t / C;
    float sc, sh;
    bn_coef(dsum, g, beta, c, H * W, sc, sh);
    size_t base = ((size_t)(b * C + c) * H + 2 * py) * W + 2 * px;
    float f0 = T[base] * sc + sh;
    float f1 = T[base + 1] * sc + sh;
    float f2 = T[base + W] * sc + sh;
    float f3 = T[base + W + 1] * sc + sh;
    feat[base] = f0; feat[base + 1] = f1; feat[base + W] = f2; feat[base + W + 1] = f3;
    A[((size_t)(b * C + c) * Hh + py) * Wh + px] = fmaxf(fmaxf(fmaxf(f0, f1), fmaxf(f2, f3)), 0.f);
}

__global__ __launch_bounds__(256) void bn_apply_np4(
    const float* __restrict__ T, const double* __restrict__ dsum,
    const float* __restrict__ g, const float* __restrict__ beta,
    float* __restrict__ feat, float* __restrict__ A, int C, int HW, int total4)
{
    int idx = blockIdx.x * 256 + threadIdx.x;
    if (idx >= total4) return;
    int e = idx * 4;
    int c = (e / HW) % C;
    float sc, sh;
    bn_coef(dsum, g, beta, c, HW, sc, sh);
    float4 t = *(const float4*)(T + e);
    float4 f = make_float4(t.x * sc + sh, t.y * sc + sh, t.z * sc + sh, t.w * sc + sh);
    *(float4*)(feat + e) = f;
    *(float4*)(A + e) = make_float4(fmaxf(f.x, 0.f), fmaxf(f.y, 0.f), fmaxf(f.z, 0.f), fmaxf(f.w, 0.f));
}

// ---------------- fused global-max(3x3) + final 1x1 adder ----------------
__global__ __launch_bounds__(256) void final_adder(
    const float* __restrict__ A, const float* __restrict__ wl, float* __restrict__ fo)
{
    __shared__ float xs[1024];
    for (int i = threadIdx.x; i < 1024; i += 256) {
        const float* p = A + (size_t)i * 9;
        float m = p[0];
#pragma unroll
        for (int j = 1; j < 9; j++) m = fmaxf(m, p[j]);
        xs[i] = m;                      // i = b*512 + c
    }
    __syncthreads();
    int o = blockIdx.x * 128 + (threadIdx.x >> 1);
    int b = threadIdx.x & 1;
    if (o >= 1000) return;
    const float* wrow = wl + (size_t)o * 512;
    const float* xb = xs + b * 512;
    double s = 0.0;
    for (int c = 0; c < 512; c += 4) {
        float4 wv = *(const float4*)&wrow[c];
        s += (double)fabsf(xb[c] - wv.x) + (double)fabsf(xb[c + 1] - wv.y)
           + (double)fabsf(xb[c + 2] - wv.z) + (double)fabsf(xb[c + 3] - wv.w);
    }
    fo[b * 1000 + o] = (float)(-s);
}

// ---------------- final BN over batch of 2 ----------------
__global__ __launch_bounds__(256) void final_bn(
    const float* __restrict__ fo, const float* __restrict__ gl, const float* __restrict__ bl,
    float* __restrict__ out)
{
    int o = blockIdx.x * 256 + threadIdx.x;
    if (o >= 1000) return;
    float v0 = fo[o], v1 = fo[1000 + o];
    float mu = 0.5f * (v0 + v1);
    float d = v0 - mu;
    float var = d * d;           // mean of squared deviations for n=2
    float iv = rsqrtf(var + (float)BN_EPS);
    float sg = iv * gl[o];
    out[o] = d * sg + bl[o];
    out[1000 + o] = -d * sg + bl[o];
}

extern "C" void kernel_launch(void* const* d_in, const int* in_sizes, int n_in,
                              void* d_out, int out_size, void* d_ws, size_t ws_size,
                              hipStream_t stream)
{
    const float* x = (const float*)d_in[0];
    const float* Wt[8]; const float* Gt[8]; const float* Bt[8];
    for (int i = 0; i < 8; i++) {
        Wt[i] = (const float*)d_in[1 + 3 * i];
        Gt[i] = (const float*)d_in[2 + 3 * i];
        Bt[i] = (const float*)d_in[3 + 3 * i];
    }
    const float* wl = (const float*)d_in[25];
    const float* gl = (const float*)d_in[26];
    const float* bl = (const float*)d_in[27];
    float* out = (float*)d_out;
    float* ws = (float*)d_ws;

    // ws layout (floats): [dsum 11008][T 1179648][A 294912][fo 2000][P 9437184]
    double* dsum = (double*)d_ws;            // 5504 doubles (per-layer BN sum/sumsq)
    float* T  = ws + 11008;
    float* A  = ws + 1190656;
    float* fo = ws + 1485568;
    float* P  = ws + 1487568;
    (void)ws_size;

    hipMemsetAsync(dsum, 0, 5504 * 8, stream);   // re-zeroed every call (graph-replay safe)

    static const int Cc[8]  = {3, 64, 128, 256, 256, 512, 512, 512};
    static const int Oc[8]  = {64, 128, 256, 256, 512, 512, 512, 512};
    static const int Hc[8]  = {96, 48, 24, 24, 12, 12, 6, 6};
    static const int RSc[8] = {1, 16, 32, 32, 64, 64, 128, 128};  // C/RS in {3,4,8}
    static const int PLc[8] = {1, 1, 0, 1, 0, 1, 0, 1};
    static const size_t foff[8] = {2000, 1181648, 1771472, 2066384,
                                   2361296, 2508752, 2656208, 2693072};
    static const int doff[8] = {0, 128, 384, 896, 1408, 2432, 3456, 4480};

    const float* cur = x;
    for (int i = 0; i < 8; i++) {
        const int C = Cc[i], O = Oc[i], H = Hc[i], Wd = Hc[i];
        const int HW = H * Wd;
        const int rs = RSc[i];
        const int TP = (i == 0) ? 4 : 6;                      // L2..L8: W in {48,24,12,6}, all %6==0
        const int TO = (i == 0) ? 2 : ((i >= 6) ? 4 : 8);
        const int OT = 16 * TO;
        const int tpr = Wd / TP;
        const int PTt = 2 * H * tpr;
        dim3 grid((PTt + 15) / 16, O / OT, rs);
        if (i == 0)
            adder_partial<4, 2, 3><<<grid, 256, 0, stream>>>(cur, Wt[i], P, C, H, Wd, O);   // CPR=3
        else if (i >= 6)
            adder_partial<6, 4, 4><<<grid, 256, 0, stream>>>(cur, Wt[i], P, C, H, Wd, O);   // CPR=4
        else if (C / rs == 8)
            adder_partial<6, 8, 8><<<grid, 256, 0, stream>>>(cur, Wt[i], P, C, H, Wd, O);   // L4,L6: 2-phase
        else
            adder_partial<6, 8, 4><<<grid, 256, 0, stream>>>(cur, Wt[i], P, C, H, Wd, O);   // L2,L3,L5

        double* dsum_l = dsum + doff[i];
        reduce_stats<<<2 * O, 256, 0, stream>>>(P, T, dsum_l, O, HW, rs);

        float* feat = out + foff[i];
        if (PLc[i]) {
            int total = 2 * O * (H / 2) * (Wd / 2);
            bn_apply_pool<<<(total + 255) / 256, 256, 0, stream>>>(T, dsum_l, Gt[i], Bt[i], feat, A, O, H, Wd, total);
        } else {
            int total4 = (2 * O * HW) >> 2;
            bn_apply_np4<<<(total4 + 255) / 256, 256, 0, stream>>>(T, dsum_l, Gt[i], Bt[i], feat, A, O, HW, total4);
        }
        cur = A;
    }
    final_adder<<<8, 256, 0, stream>>>(A, wl, fo);   // A = (2,512,3,3) after layer-8 pool+relu
    final_bn<<<4, 256, 0, stream>>>(fo, gl, bl, out);
}

// Round 16
// 383.477 us; speedup vs baseline: 1.1226x; 1.1226x over previous
//
#include <hip/hip_runtime.h>

#define BN_EPS 1e-5

// ---------------- adder conv 3x3 pad1, split-K partial -> plain stores to P[z] ----------------
// FROZEN R14 kernel (374us best): single-phase staging, asm 2-VALU/element inner op, VGPR 52.
// Three structural-edit attempts (TO=4, 2-phase x2) all regressed via regalloc perturbation.
template<int TP, int TO, int CPR>
__global__ __launch_bounds__(256) void adder_partial(
    const float* __restrict__ x, const float* __restrict__ w,
    float* __restrict__ P, int C, int H, int W, int O)
{
    constexpr int OT = 16 * TO;          // o-tile per block
    constexpr int PADOT = OT + 4;
    constexpr int NK = CPR * 9;
    constexpr int NITEMS = NK * OT;
    constexpr int ITERS = (NITEMS + 255) / 256;
    constexpr int BATCH = (ITERS < 8) ? ITERS : 8;
    __shared__ float w_s[NK][PADOT];

    const int tid = threadIdx.x;
    const int tx = tid & 15, ty = tid >> 4;
    const int o_blk = blockIdx.y * OT;
    const int tpr = W / TP;              // tiles per row (exact: W%TP==0 for all layer configs)
    const int PT = 2 * H * tpr;          // B=2
    const int pt = blockIdx.x * 16 + tx;
    const bool act = pt < PT;
    int b = 0, y = 0, x0 = 0;
    if (act) { int t = pt; x0 = (t % tpr) * TP; t /= tpr; y = t % H; b = t / H; }
    const int c0 = blockIdx.z * CPR;

    // ---- staging: fully unrolled, batched loads (8 in flight), then batched LDS writes ----
    const float* wbase = w + ((size_t)o_blk * C + c0) * 9;   // + ol*C*9 + kk
    const int c9 = C * 9;
#pragma unroll
    for (int g0 = 0; g0 < ITERS; g0 += BATCH) {
        float tmp[BATCH];
#pragma unroll
        for (int u = 0; u < BATCH; ++u) {
            int it = g0 + u;
            if (it < ITERS) {
                int idx = tid + it * 256;
                int ol = idx / NK, kk = idx - ol * NK;
                if (idx < NITEMS) tmp[u] = wbase[(size_t)ol * c9 + kk];
            }
        }
#pragma unroll
        for (int u = 0; u < BATCH; ++u) {
            int it = g0 + u;
            if (it < ITERS) {
                int idx = tid + it * 256;
                int ol = idx / NK, kk = idx - ol * NK;
                if (idx < NITEMS) w_s[kk][ol] = tmp[u];
            }
        }
    }
    __syncthreads();

    bool rv[3]; int yoff[3];
#pragma unroll
    for (int dy = 0; dy < 3; ++dy) {
        int yy = y + dy - 1;
        bool v = act && (yy >= 0) && (yy < H);
        rv[dy] = v; yoff[dy] = (v ? yy : 0) * W;
    }
    const bool lok = (x0 > 0), rok = (x0 + TP) < W;
    const int off0 = lok ? -1 : 0;
    const int offT = rok ? TP : (TP - 1);

    float acc[TO][TP] = {};

    for (int cc = 0; cc < CPR; ++cc) {
        const float* xc = x + ((size_t)(b * C + c0 + cc)) * H * W;
#pragma unroll
        for (int dy = 0; dy < 3; ++dy) {
            const float* rp = xc + yoff[dy] + x0;
            float xr[TP + 2];
            if constexpr (TP == 4) {
                float4 v = *(const float4*)rp;          // 16B-aligned: W%4==0, x0%4==0
                xr[1] = rv[dy] ? v.x : 0.f;
                xr[2] = rv[dy] ? v.y : 0.f;
                xr[3] = rv[dy] ? v.z : 0.f;
                xr[4] = rv[dy] ? v.w : 0.f;
                float vl = rp[off0]; xr[0]      = (rv[dy] && lok) ? vl : 0.f;
                float vr = rp[offT]; xr[TP + 1] = (rv[dy] && rok) ? vr : 0.f;
            } else {                                     // TP == 6: x0%2==0 -> 8B-aligned rows
                float2 a0 = *(const float2*)rp;
                float2 a1 = *(const float2*)(rp + 2);
                float2 a2 = *(const float2*)(rp + 4);
                xr[1] = rv[dy] ? a0.x : 0.f;
                xr[2] = rv[dy] ? a0.y : 0.f;
                xr[3] = rv[dy] ? a1.x : 0.f;
                xr[4] = rv[dy] ? a1.y : 0.f;
                xr[5] = rv[dy] ? a2.x : 0.f;
                xr[6] = rv[dy] ? a2.y : 0.f;
                float vl = rp[off0]; xr[0]      = (rv[dy] && lok) ? vl : 0.f;
                float vr = rp[offT]; xr[TP + 1] = (rv[dy] && rok) ? vr : 0.f;
            }
#pragma unroll
            for (int dx = 0; dx < 3; ++dx) {
                const float* wrow = &w_s[cc * 9 + dy * 3 + dx][ty * TO];
                float wv[TO];
                if constexpr (TO == 8) {
                    float4 wa = *(const float4*)wrow;
                    float4 wb = *(const float4*)(wrow + 4);
                    wv[0]=wa.x; wv[1]=wa.y; wv[2]=wa.z; wv[3]=wa.w;
                    wv[4]=wb.x; wv[5]=wb.y; wv[6]=wb.z; wv[7]=wb.w;
                } else if constexpr (TO == 4) {
                    float4 wa = *(const float4*)wrow;
                    wv[0]=wa.x; wv[1]=wa.y; wv[2]=wa.z; wv[3]=wa.w;
                } else {                                 // TO == 2
                    float2 wa = *(const float2*)wrow;
                    wv[0]=wa.x; wv[1]=wa.y;
                }
#pragma unroll
                for (int i = 0; i < TO; i++)
#pragma unroll
                    for (int p = 0; p < TP; p++) {
                        float d;
                        // exactly 2 VALU: d = x - w; acc += |d| (abs as VOP3 source modifier)
                        asm("v_sub_f32 %1, %2, %3\n\t"
                            "v_add_f32_e64 %0, %0, |%1|"
                            : "+v"(acc[i][p]), "=&v"(d)
                            : "v"(xr[p + dx]), "v"(wv[i]));
                    }
            }
        }
    }
    if (act) {
        float* Pz = P + (size_t)blockIdx.z * ((size_t)2 * O * H * W);
        const int o0 = o_blk + ty * TO;
#pragma unroll
        for (int i = 0; i < TO; i++) {
            float* Tp = Pz + ((size_t)(b * O + (o0 + i)) * H + y) * W + x0;
            if constexpr (TP == 4) {
                *(float4*)Tp = make_float4(-acc[i][0], -acc[i][1], -acc[i][2], -acc[i][3]);
            } else {
                *(float2*)Tp       = make_float2(-acc[i][0], -acc[i][1]);
                *(float2*)(Tp + 2) = make_float2(-acc[i][2], -acc[i][3]);
                *(float2*)(Tp + 4) = make_float2(-acc[i][4], -acc[i][5]);
            }
        }
    }
}

// ---------------- fused: z-reduce P -> t, block-local BN stats, BN apply + pool/relu ----------
// One block per channel c, covering BOTH batches -> stats complete block-locally (no atomics,
// no dsum buffer, no memset). T kept in LDS where 2*HW <= 4608 floats (all layers but L1);
// L1 routes t through global T (+threadfence_block). Replaces reduce_stats + bn_apply.
template<int POOL, int TLDS>
__global__ __launch_bounds__(256) void reduce_bn_apply(
    const float* __restrict__ P, float* __restrict__ T,
    const float* __restrict__ g, const float* __restrict__ beta,
    float* __restrict__ feat, float* __restrict__ A,
    int O, int H, int W, int RS)
{
    __shared__ double sh1[256];
    __shared__ double sh2[256];
    __shared__ float coef[2];
    constexpr int TBUF = TLDS ? 4608 : 4;
    __shared__ __align__(16) float tbuf[TBUF];

    const int tid = threadIdx.x;
    const int c = blockIdx.x;
    const int HW = H * W;
    const int n4 = HW >> 2;                     // HW % 4 == 0 for all layers
    const size_t outsz4 = (size_t)2 * O * n4;
    double a = 0.0, q = 0.0;

    for (int idx = tid; idx < 2 * n4; idx += 256) {
        int b = (idx >= n4) ? 1 : 0;
        int i4 = idx - b * n4;
        const float4* P4 = (const float4*)P + (size_t)(b * O + c) * n4 + i4;
        float4 s0 = make_float4(0.f, 0.f, 0.f, 0.f);
        float4 s1 = make_float4(0.f, 0.f, 0.f, 0.f);
        int z = 0;
        for (; z + 1 < RS; z += 2) {
            float4 v0 = P4[(size_t)z * outsz4];
            float4 v1 = P4[(size_t)(z + 1) * outsz4];
            s0.x += v0.x; s0.y += v0.y; s0.z += v0.z; s0.w += v0.w;
            s1.x += v1.x; s1.y += v1.y; s1.z += v1.z; s1.w += v1.w;
        }
        if (z < RS) {
            float4 v = P4[(size_t)z * outsz4];
            s0.x += v.x; s0.y += v.y; s0.z += v.z; s0.w += v.w;
        }
        s0.x += s1.x; s0.y += s1.y; s0.z += s1.z; s0.w += s1.w;
        if constexpr (TLDS) ((float4*)tbuf)[idx] = s0;
        else ((float4*)(T + (size_t)(b * O + c) * HW))[i4] = s0;
        a += (double)s0.x + (double)s0.y + (double)s0.z + (double)s0.w;
        q += (double)s0.x * s0.x + (double)s0.y * s0.y
           + (double)s0.z * s0.z + (double)s0.w * s0.w;
    }
    if constexpr (!TLDS) __threadfence_block();
    sh1[tid] = a; sh2[tid] = q;
    __syncthreads();
    for (int s = 128; s > 0; s >>= 1) {
        if (tid < s) { sh1[tid] += sh1[tid + s]; sh2[tid] += sh2[tid + s]; }
        __syncthreads();
    }
    if (tid == 0) {
        double n = 2.0 * (double)HW;
        double mu = sh1[0] / n;
        double var = sh2[0] / n - mu * mu;
        double inv = 1.0 / sqrt(var + (double)BN_EPS);
        double s = (double)g[c] * inv;
        coef[0] = (float)s;
        coef[1] = (float)((double)beta[c] - mu * s);
    }
    __syncthreads();
    const float sc = coef[0], shv = coef[1];

    if constexpr (POOL) {
        const int Wh = W >> 1, Hh = H >> 1, np = Hh * Wh;
        for (int idx = tid; idx < 2 * np; idx += 256) {
            int b = (idx >= np) ? 1 : 0;
            int r = idx - b * np;
            int py = r / Wh, px = r - py * Wh;
            int e = (2 * py) * W + 2 * px;
            float t0, t1, t2, t3;
            if constexpr (TLDS) {
                const float* tp = tbuf + b * HW + e;
                t0 = tp[0]; t1 = tp[1]; t2 = tp[W]; t3 = tp[W + 1];
            } else {
                const float* tp = T + (size_t)(b * O + c) * HW + e;
                t0 = tp[0]; t1 = tp[1]; t2 = tp[W]; t3 = tp[W + 1];
            }
            float f0 = t0 * sc + shv, f1 = t1 * sc + shv;
            float f2 = t2 * sc + shv, f3 = t3 * sc + shv;
            float* fp = feat + (size_t)(b * O + c) * HW + e;
            fp[0] = f0; fp[1] = f1; fp[W] = f2; fp[W + 1] = f3;
            A[((size_t)(b * O + c) * Hh + py) * Wh + px] =
                fmaxf(fmaxf(fmaxf(f0, f1), fmaxf(f2, f3)), 0.f);
        }
    } else {
        for (int idx = tid; idx < 2 * n4; idx += 256) {
            int b = (idx >= n4) ? 1 : 0;
            int i4 = idx - b * n4;
            float4 t;
            if constexpr (TLDS) t = ((float4*)tbuf)[idx];
            else t = ((const float4*)(T + (size_t)(b * O + c) * HW))[i4];
            float4 f = make_float4(t.x * sc + shv, t.y * sc + shv,
                                   t.z * sc + shv, t.w * sc + shv);
            ((float4*)(feat + (size_t)(b * O + c) * HW))[i4] = f;
            ((float4*)(A + (size_t)(b * O + c) * HW))[i4] =
                make_float4(fmaxf(f.x, 0.f), fmaxf(f.y, 0.f), fmaxf(f.z, 0.f), fmaxf(f.w, 0.f));
        }
    }
}

// ---------------- fused global-max(3x3) + final 1x1 adder ----------------
__global__ __launch_bounds__(256) void final_adder(
    const float* __restrict__ A, const float* __restrict__ wl, float* __restrict__ fo)
{
    __shared__ float xs[1024];
    for (int i = threadIdx.x; i < 1024; i += 256) {
        const float* p = A + (size_t)i * 9;
        float m = p[0];
#pragma unroll
        for (int j = 1; j < 9; j++) m = fmaxf(m, p[j]);
        xs[i] = m;                      // i = b*512 + c
    }
    __syncthreads();
    int o = blockIdx.x * 128 + (threadIdx.x >> 1);
    int b = threadIdx.x & 1;
    if (o >= 1000) return;
    const float* wrow = wl + (size_t)o * 512;
    const float* xb = xs + b * 512;
    double s = 0.0;
    for (int c = 0; c < 512; c += 4) {
        float4 wv = *(const float4*)&wrow[c];
        s += (double)fabsf(xb[c] - wv.x) + (double)fabsf(xb[c + 1] - wv.y)
           + (double)fabsf(xb[c + 2] - wv.z) + (double)fabsf(xb[c + 3] - wv.w);
    }
    fo[b * 1000 + o] = (float)(-s);
}

// ---------------- final BN over batch of 2 ----------------
__global__ __launch_bounds__(256) void final_bn(
    const float* __restrict__ fo, const float* __restrict__ gl, const float* __restrict__ bl,
    float* __restrict__ out)
{
    int o = blockIdx.x * 256 + threadIdx.x;
    if (o >= 1000) return;
    float v0 = fo[o], v1 = fo[1000 + o];
    float mu = 0.5f * (v0 + v1);
    float d = v0 - mu;
    float var = d * d;           // mean of squared deviations for n=2
    float iv = rsqrtf(var + (float)BN_EPS);
    float sg = iv * gl[o];
    out[o] = d * sg + bl[o];
    out[1000 + o] = -d * sg + bl[o];
}

extern "C" void kernel_launch(void* const* d_in, const int* in_sizes, int n_in,
                              void* d_out, int out_size, void* d_ws, size_t ws_size,
                              hipStream_t stream)
{
    const float* x = (const float*)d_in[0];
    const float* Wt[8]; const float* Gt[8]; const float* Bt[8];
    for (int i = 0; i < 8; i++) {
        Wt[i] = (const float*)d_in[1 + 3 * i];
        Gt[i] = (const float*)d_in[2 + 3 * i];
        Bt[i] = (const float*)d_in[3 + 3 * i];
    }
    const float* wl = (const float*)d_in[25];
    const float* gl = (const float*)d_in[26];
    const float* bl = (const float*)d_in[27];
    float* out = (float*)d_out;
    float* ws = (float*)d_ws;

    // ws layout (floats): [T 1179648 (L1 only)][A 294912][fo 2000][P 9437184]
    float* T  = ws;
    float* A  = ws + 1179648;
    float* fo = ws + 1474560;
    float* P  = ws + 1476560;                // *4B = 5906240, 16B-aligned
    (void)ws_size;

    static const int Cc[8]  = {3, 64, 128, 256, 256, 512, 512, 512};
    static const int Oc[8]  = {64, 128, 256, 256, 512, 512, 512, 512};
    static const int Hc[8]  = {96, 48, 24, 24, 12, 12, 6, 6};
    static const int RSc[8] = {1, 16, 32, 32, 64, 64, 128, 128};  // C/RS in {3,4,8}
    static const int PLc[8] = {1, 1, 0, 1, 0, 1, 0, 1};
    static const size_t foff[8] = {2000, 1181648, 1771472, 2066384,
                                   2361296, 2508752, 2656208, 2693072};

    const float* cur = x;
    for (int i = 0; i < 8; i++) {
        const int C = Cc[i], O = Oc[i], H = Hc[i], Wd = Hc[i];
        const int rs = RSc[i];
        const int TP = (i == 0) ? 4 : 6;                      // L2..L8: W in {48,24,12,6}, all %6==0
        const int TO = (i == 0) ? 2 : ((i >= 6) ? 4 : 8);
        const int OT = 16 * TO;
        const int tpr = Wd / TP;
        const int PTt = 2 * H * tpr;
        dim3 grid((PTt + 15) / 16, O / OT, rs);
        if (i == 0)
            adder_partial<4, 2, 3><<<grid, 256, 0, stream>>>(cur, Wt[i], P, C, H, Wd, O);   // CPR=3
        else if (i >= 6)
            adder_partial<6, 4, 4><<<grid, 256, 0, stream>>>(cur, Wt[i], P, C, H, Wd, O);   // CPR=4
        else if (C / rs == 8)
            adder_partial<6, 8, 8><<<grid, 256, 0, stream>>>(cur, Wt[i], P, C, H, Wd, O);   // L4,L6
        else
            adder_partial<6, 8, 4><<<grid, 256, 0, stream>>>(cur, Wt[i], P, C, H, Wd, O);   // L2,L3,L5

        float* feat = out + foff[i];
        if (i == 0)
            reduce_bn_apply<1, 0><<<O, 256, 0, stream>>>(P, T, Gt[i], Bt[i], feat, A, O, H, Wd, rs);
        else if (PLc[i])
            reduce_bn_apply<1, 1><<<O, 256, 0, stream>>>(P, T, Gt[i], Bt[i], feat, A, O, H, Wd, rs);
        else
            reduce_bn_apply<0, 1><<<O, 256, 0, stream>>>(P, T, Gt[i], Bt[i], feat, A, O, H, Wd, rs);
        cur = A;
    }
    final_adder<<<8, 256, 0, stream>>>(A, wl, fo);   // A = (2,512,3,3) after layer-8 pool+relu
    final_bn<<<4, 256, 0, stream>>>(fo, gl, bl, out);
}

// Round 17
// 372.589 us; speedup vs baseline: 1.1554x; 1.0292x over previous
//
#include <hip/hip_runtime.h>

#define BN_EPS 1e-5

// ---------------- adder conv 3x3 pad1, split-K partial -> plain stores to P[z] ----------------
// R14-frozen inner loop (asm 2-VALU/element, VGPR 52). R17: TO=4 on L2..L6 doubles grid.y ->
// 1536 blocks = 6 blocks/CU = 24 waves/CU (grid size was the occupancy binder at 768 blocks;
// LDS 19.6/9.8KB and VGPR ~40 both allow it). LDS-read:VALU ratio unchanged vs TO=8.
template<int TP, int TO, int CPR>
__global__ __launch_bounds__(256) void adder_partial(
    const float* __restrict__ x, const float* __restrict__ w,
    float* __restrict__ P, int C, int H, int W, int O)
{
    constexpr int OT = 16 * TO;          // o-tile per block
    constexpr int PADOT = OT + 4;
    constexpr int NK = CPR * 9;
    constexpr int NITEMS = NK * OT;
    constexpr int ITERS = (NITEMS + 255) / 256;
    constexpr int BATCH = (ITERS < 8) ? ITERS : 8;
    __shared__ float w_s[NK][PADOT];

    const int tid = threadIdx.x;
    const int tx = tid & 15, ty = tid >> 4;
    const int o_blk = blockIdx.y * OT;
    const int tpr = W / TP;              // tiles per row (exact: W%TP==0 for all layer configs)
    const int PT = 2 * H * tpr;          // B=2
    const int pt = blockIdx.x * 16 + tx;
    const bool act = pt < PT;
    int b = 0, y = 0, x0 = 0;
    if (act) { int t = pt; x0 = (t % tpr) * TP; t /= tpr; y = t % H; b = t / H; }
    const int c0 = blockIdx.z * CPR;

    // ---- staging: fully unrolled, batched loads (8 in flight), then batched LDS writes ----
    const float* wbase = w + ((size_t)o_blk * C + c0) * 9;   // + ol*C*9 + kk
    const int c9 = C * 9;
#pragma unroll
    for (int g0 = 0; g0 < ITERS; g0 += BATCH) {
        float tmp[BATCH];
#pragma unroll
        for (int u = 0; u < BATCH; ++u) {
            int it = g0 + u;
            if (it < ITERS) {
                int idx = tid + it * 256;
                int ol = idx / NK, kk = idx - ol * NK;
                if (idx < NITEMS) tmp[u] = wbase[(size_t)ol * c9 + kk];
            }
        }
#pragma unroll
        for (int u = 0; u < BATCH; ++u) {
            int it = g0 + u;
            if (it < ITERS) {
                int idx = tid + it * 256;
                int ol = idx / NK, kk = idx - ol * NK;
                if (idx < NITEMS) w_s[kk][ol] = tmp[u];
            }
        }
    }
    __syncthreads();

    bool rv[3]; int yoff[3];
#pragma unroll
    for (int dy = 0; dy < 3; ++dy) {
        int yy = y + dy - 1;
        bool v = act && (yy >= 0) && (yy < H);
        rv[dy] = v; yoff[dy] = (v ? yy : 0) * W;
    }
    const bool lok = (x0 > 0), rok = (x0 + TP) < W;
    const int off0 = lok ? -1 : 0;
    const int offT = rok ? TP : (TP - 1);

    float acc[TO][TP] = {};

    for (int cc = 0; cc < CPR; ++cc) {
        const float* xc = x + ((size_t)(b * C + c0 + cc)) * H * W;
#pragma unroll
        for (int dy = 0; dy < 3; ++dy) {
            const float* rp = xc + yoff[dy] + x0;
            float xr[TP + 2];
            if constexpr (TP == 4) {
                float4 v = *(const float4*)rp;          // 16B-aligned: W%4==0, x0%4==0
                xr[1] = rv[dy] ? v.x : 0.f;
                xr[2] = rv[dy] ? v.y : 0.f;
                xr[3] = rv[dy] ? v.z : 0.f;
                xr[4] = rv[dy] ? v.w : 0.f;
                float vl = rp[off0]; xr[0]      = (rv[dy] && lok) ? vl : 0.f;
                float vr = rp[offT]; xr[TP + 1] = (rv[dy] && rok) ? vr : 0.f;
            } else {                                     // TP == 6: x0%2==0 -> 8B-aligned rows
                float2 a0 = *(const float2*)rp;
                float2 a1 = *(const float2*)(rp + 2);
                float2 a2 = *(const float2*)(rp + 4);
                xr[1] = rv[dy] ? a0.x : 0.f;
                xr[2] = rv[dy] ? a0.y : 0.f;
                xr[3] = rv[dy] ? a1.x : 0.f;
                xr[4] = rv[dy] ? a1.y : 0.f;
                xr[5] = rv[dy] ? a2.x : 0.f;
                xr[6] = rv[dy] ? a2.y : 0.f;
                float vl = rp[off0]; xr[0]      = (rv[dy] && lok) ? vl : 0.f;
                float vr = rp[offT]; xr[TP + 1] = (rv[dy] && rok) ? vr : 0.f;
            }
#pragma unroll
            for (int dx = 0; dx < 3; ++dx) {
                const float* wrow = &w_s[cc * 9 + dy * 3 + dx][ty * TO];
                float wv[TO];
                if constexpr (TO == 8) {
                    float4 wa = *(const float4*)wrow;
                    float4 wb = *(const float4*)(wrow + 4);
                    wv[0]=wa.x; wv[1]=wa.y; wv[2]=wa.z; wv[3]=wa.w;
                    wv[4]=wb.x; wv[5]=wb.y; wv[6]=wb.z; wv[7]=wb.w;
                } else if constexpr (TO == 4) {
                    float4 wa = *(const float4*)wrow;    // rows are 16B-aligned (PADOT*4 % 16 == 0)
                    wv[0]=wa.x; wv[1]=wa.y; wv[2]=wa.z; wv[3]=wa.w;
                } else {                                 // TO == 2
                    float2 wa = *(const float2*)wrow;
                    wv[0]=wa.x; wv[1]=wa.y;
                }
#pragma unroll
                for (int i = 0; i < TO; i++)
#pragma unroll
                    for (int p = 0; p < TP; p++) {
                        float d;
                        // exactly 2 VALU: d = x - w; acc += |d| (abs as VOP3 source modifier)
                        asm("v_sub_f32 %1, %2, %3\n\t"
                            "v_add_f32_e64 %0, %0, |%1|"
                            : "+v"(acc[i][p]), "=&v"(d)
                            : "v"(xr[p + dx]), "v"(wv[i]));
                    }
            }
        }
    }
    if (act) {
        float* Pz = P + (size_t)blockIdx.z * ((size_t)2 * O * H * W);
        const int o0 = o_blk + ty * TO;
#pragma unroll
        for (int i = 0; i < TO; i++) {
            float* Tp = Pz + ((size_t)(b * O + (o0 + i)) * H + y) * W + x0;
            if constexpr (TP == 4) {
                *(float4*)Tp = make_float4(-acc[i][0], -acc[i][1], -acc[i][2], -acc[i][3]);
            } else {
                *(float2*)Tp       = make_float2(-acc[i][0], -acc[i][1]);
                *(float2*)(Tp + 2) = make_float2(-acc[i][2], -acc[i][3]);
                *(float2*)(Tp + 4) = make_float2(-acc[i][4], -acc[i][5]);
            }
        }
    }
}

// ---------------- z-reduce P -> T, fused BN sum/sumsq (2 double atomics per block) ----------------
__global__ __launch_bounds__(256) void reduce_stats(
    const float* __restrict__ P, float* __restrict__ T, double* __restrict__ dsum,
    int O, int HW, int RS)
{
    __shared__ double sh1[256];
    __shared__ double sh2[256];
    const int bc = blockIdx.x;          // b*O + c
    const int c = bc % O;
    const int n4 = HW >> 2;             // HW % 4 == 0 for all layers
    const size_t outsz4 = (size_t)2 * O * n4;
    const float4* P4 = (const float4*)P + (size_t)bc * n4;
    float4* T4 = (float4*)T + (size_t)bc * n4;
    double a = 0.0, q = 0.0;
    for (int i4 = threadIdx.x; i4 < n4; i4 += 256) {
        float4 s0 = make_float4(0.f, 0.f, 0.f, 0.f);
        float4 s1 = make_float4(0.f, 0.f, 0.f, 0.f);
        int z = 0;
        for (; z + 1 < RS; z += 2) {
            float4 v0 = P4[(size_t)z * outsz4 + i4];
            float4 v1 = P4[(size_t)(z + 1) * outsz4 + i4];
            s0.x += v0.x; s0.y += v0.y; s0.z += v0.z; s0.w += v0.w;
            s1.x += v1.x; s1.y += v1.y; s1.z += v1.z; s1.w += v1.w;
        }
        if (z < RS) {
            float4 v = P4[(size_t)z * outsz4 + i4];
            s0.x += v.x; s0.y += v.y; s0.z += v.z; s0.w += v.w;
        }
        s0.x += s1.x; s0.y += s1.y; s0.z += s1.z; s0.w += s1.w;
        T4[i4] = s0;
        a += (double)s0.x + (double)s0.y + (double)s0.z + (double)s0.w;
        q += (double)s0.x * s0.x + (double)s0.y * s0.y
           + (double)s0.z * s0.z + (double)s0.w * s0.w;
    }
    sh1[threadIdx.x] = a; sh2[threadIdx.x] = q;
    __syncthreads();
    for (int s = 128; s > 0; s >>= 1) {
        if (threadIdx.x < s) { sh1[threadIdx.x] += sh1[threadIdx.x + s]; sh2[threadIdx.x] += sh2[threadIdx.x + s]; }
        __syncthreads();
    }
    if (threadIdx.x == 0) {
        unsafeAtomicAdd(&dsum[2 * c],     sh1[0]);
        unsafeAtomicAdd(&dsum[2 * c + 1], sh2[0]);
    }
}

__device__ __forceinline__ void bn_coef(const double* __restrict__ dsum,
                                        const float* __restrict__ g,
                                        const float* __restrict__ beta,
                                        int c, int HW, float& sc, float& sh)
{
    double n = 2.0 * (double)HW;
    double mu = dsum[2 * c] / n;
    double var = dsum[2 * c + 1] / n - mu * mu;
    double inv = 1.0 / sqrt(var + (double)BN_EPS);
    double s = (double)g[c] * inv;
    sc = (float)s;
    sh = (float)((double)beta[c] - mu * s);
}

// ---------------- BN apply (inline coef) + feature write + maxpool2 + relu ----------------
__global__ __launch_bounds__(256) void bn_apply_pool(
    const float* __restrict__ T, const double* __restrict__ dsum,
    const float* __restrict__ g, const float* __restrict__ beta,
    float* __restrict__ feat, float* __restrict__ A, int C, int H, int W, int total)
{
    int idx = blockIdx.x * 256 + threadIdx.x;
    if (idx >= total) return;
    int Wh = W >> 1, Hh = H >> 1;
    int px = idx % Wh; int t = idx / Wh;
    int py = t % Hh; t /= Hh;
    int c = t % C; int b = t / C;
    float sc, sh;
    bn_coef(dsum, g, beta, c, H * W, sc, sh);
    size_t base = ((size_t)(b * C + c) * H + 2 * py) * W + 2 * px;
    float f0 = T[base] * sc + sh;
    float f1 = T[base + 1] * sc + sh;
    float f2 = T[base + W] * sc + sh;
    float f3 = T[base + W + 1] * sc + sh;
    feat[base] = f0; feat[base + 1] = f1; feat[base + W] = f2; feat[base + W + 1] = f3;
    A[((size_t)(b * C + c) * Hh + py) * Wh + px] = fmaxf(fmaxf(fmaxf(f0, f1), fmaxf(f2, f3)), 0.f);
}

__global__ __launch_bounds__(256) void bn_apply_np4(
    const float* __restrict__ T, const double* __restrict__ dsum,
    const float* __restrict__ g, const float* __restrict__ beta,
    float* __restrict__ feat, float* __restrict__ A, int C, int HW, int total4)
{
    int idx = blockIdx.x * 256 + threadIdx.x;
    if (idx >= total4) return;
    int e = idx * 4;
    int c = (e / HW) % C;
    float sc, sh;
    bn_coef(dsum, g, beta, c, HW, sc, sh);
    float4 t = *(const float4*)(T + e);
    float4 f = make_float4(t.x * sc + sh, t.y * sc + sh, t.z * sc + sh, t.w * sc + sh);
    *(float4*)(feat + e) = f;
    *(float4*)(A + e) = make_float4(fmaxf(f.x, 0.f), fmaxf(f.y, 0.f), fmaxf(f.z, 0.f), fmaxf(f.w, 0.f));
}

// ---------------- fused global-max(3x3) + final 1x1 adder ----------------
__global__ __launch_bounds__(256) void final_adder(
    const float* __restrict__ A, const float* __restrict__ wl, float* __restrict__ fo)
{
    __shared__ float xs[1024];
    for (int i = threadIdx.x; i < 1024; i += 256) {
        const float* p = A + (size_t)i * 9;
        float m = p[0];
#pragma unroll
        for (int j = 1; j < 9; j++) m = fmaxf(m, p[j]);
        xs[i] = m;                      // i = b*512 + c
    }
    __syncthreads();
    int o = blockIdx.x * 128 + (threadIdx.x >> 1);
    int b = threadIdx.x & 1;
    if (o >= 1000) return;
    const float* wrow = wl + (size_t)o * 512;
    const float* xb = xs + b * 512;
    double s = 0.0;
    for (int c = 0; c < 512; c += 4) {
        float4 wv = *(const float4*)&wrow[c];
        s += (double)fabsf(xb[c] - wv.x) + (double)fabsf(xb[c + 1] - wv.y)
           + (double)fabsf(xb[c + 2] - wv.z) + (double)fabsf(xb[c + 3] - wv.w);
    }
    fo[b * 1000 + o] = (float)(-s);
}

// ---------------- final BN over batch of 2 ----------------
__global__ __launch_bounds__(256) void final_bn(
    const float* __restrict__ fo, const float* __restrict__ gl, const float* __restrict__ bl,
    float* __restrict__ out)
{
    int o = blockIdx.x * 256 + threadIdx.x;
    if (o >= 1000) return;
    float v0 = fo[o], v1 = fo[1000 + o];
    float mu = 0.5f * (v0 + v1);
    float d = v0 - mu;
    float var = d * d;           // mean of squared deviations for n=2
    float iv = rsqrtf(var + (float)BN_EPS);
    float sg = iv * gl[o];
    out[o] = d * sg + bl[o];
    out[1000 + o] = -d * sg + bl[o];
}

extern "C" void kernel_launch(void* const* d_in, const int* in_sizes, int n_in,
                              void* d_out, int out_size, void* d_ws, size_t ws_size,
                              hipStream_t stream)
{
    const float* x = (const float*)d_in[0];
    const float* Wt[8]; const float* Gt[8]; const float* Bt[8];
    for (int i = 0; i < 8; i++) {
        Wt[i] = (const float*)d_in[1 + 3 * i];
        Gt[i] = (const float*)d_in[2 + 3 * i];
        Bt[i] = (const float*)d_in[3 + 3 * i];
    }
    const float* wl = (const float*)d_in[25];
    const float* gl = (const float*)d_in[26];
    const float* bl = (const float*)d_in[27];
    float* out = (float*)d_out;
    float* ws = (float*)d_ws;

    // ws layout (floats): [dsum 11008][T 1179648][A 294912][fo 2000][P 9437184]
    double* dsum = (double*)d_ws;            // 5504 doubles (per-layer BN sum/sumsq)
    float* T  = ws + 11008;
    float* A  = ws + 1190656;
    float* fo = ws + 1485568;
    float* P  = ws + 1487568;
    (void)ws_size;

    hipMemsetAsync(dsum, 0, 5504 * 8, stream);   // re-zeroed every call (graph-replay safe)

    static const int Cc[8]  = {3, 64, 128, 256, 256, 512, 512, 512};
    static const int Oc[8]  = {64, 128, 256, 256, 512, 512, 512, 512};
    static const int Hc[8]  = {96, 48, 24, 24, 12, 12, 6, 6};
    static const int RSc[8] = {1, 16, 32, 32, 64, 64, 128, 128};  // C/RS in {3,4,8}
    static const int TOc[8] = {2, 4, 4, 4, 4, 4, 4, 4};           // R17: TO=4 -> 1536-block grids
    static const int PLc[8] = {1, 1, 0, 1, 0, 1, 0, 1};
    static const size_t foff[8] = {2000, 1181648, 1771472, 2066384,
                                   2361296, 2508752, 2656208, 2693072};
    static const int doff[8] = {0, 128, 384, 896, 1408, 2432, 3456, 4480};

    const float* cur = x;
    for (int i = 0; i < 8; i++) {
        const int C = Cc[i], O = Oc[i], H = Hc[i], Wd = Hc[i];
        const int HW = H * Wd;
        const int rs = RSc[i];
        const int TP = (i == 0) ? 4 : 6;                      // L2..L8: W in {48,24,12,6}, all %6==0
        const int OT = 16 * TOc[i];
        const int tpr = Wd / TP;
        const int PTt = 2 * H * tpr;
        dim3 grid((PTt + 15) / 16, O / OT, rs);
        if (i == 0)
            adder_partial<4, 2, 3><<<grid, 256, 0, stream>>>(cur, Wt[i], P, C, H, Wd, O);   // CPR=3
        else if (C / rs == 8)
            adder_partial<6, 4, 8><<<grid, 256, 0, stream>>>(cur, Wt[i], P, C, H, Wd, O);   // L4,L6
        else
            adder_partial<6, 4, 4><<<grid, 256, 0, stream>>>(cur, Wt[i], P, C, H, Wd, O);   // L2,3,5,7,8

        double* dsum_l = dsum + doff[i];
        reduce_stats<<<2 * O, 256, 0, stream>>>(P, T, dsum_l, O, HW, rs);

        float* feat = out + foff[i];
        if (PLc[i]) {
            int total = 2 * O * (H / 2) * (Wd / 2);
            bn_apply_pool<<<(total + 255) / 256, 256, 0, stream>>>(T, dsum_l, Gt[i], Bt[i], feat, A, O, H, Wd, total);
        } else {
            int total4 = (2 * O * HW) >> 2;
            bn_apply_np4<<<(total4 + 255) / 256, 256, 0, stream>>>(T, dsum_l, Gt[i], Bt[i], feat, A, O, HW, total4);
        }
        cur = A;
    }
    final_adder<<<8, 256, 0, stream>>>(A, wl, fo);   // A = (2,512,3,3) after layer-8 pool+relu
    final_bn<<<4, 256, 0, stream>>>(fo, gl, bl, out);
}

// Round 18
// 372.142 us; speedup vs baseline: 1.1568x; 1.0012x over previous
//
#include <hip/hip_runtime.h>

#define BN_EPS 1e-5

// ---------------- adder conv 3x3 pad1, split-K partial -> plain stores to P[z] ----------------
// FROZEN R17 adder (372us best): TO=4 grids (1536 blocks L2..L6), asm 2-VALU/element inner op,
// VGPR 32, VALUBusy 71%, Occ 45%. Do not restructure (3 regalloc regressions on record).
template<int TP, int TO, int CPR>
__global__ __launch_bounds__(256) void adder_partial(
    const float* __restrict__ x, const float* __restrict__ w,
    float* __restrict__ P, int C, int H, int W, int O)
{
    constexpr int OT = 16 * TO;          // o-tile per block
    constexpr int PADOT = OT + 4;
    constexpr int NK = CPR * 9;
    constexpr int NITEMS = NK * OT;
    constexpr int ITERS = (NITEMS + 255) / 256;
    constexpr int BATCH = (ITERS < 8) ? ITERS : 8;
    __shared__ float w_s[NK][PADOT];

    const int tid = threadIdx.x;
    const int tx = tid & 15, ty = tid >> 4;
    const int o_blk = blockIdx.y * OT;
    const int tpr = W / TP;              // tiles per row (exact: W%TP==0 for all layer configs)
    const int PT = 2 * H * tpr;          // B=2
    const int pt = blockIdx.x * 16 + tx;
    const bool act = pt < PT;
    int b = 0, y = 0, x0 = 0;
    if (act) { int t = pt; x0 = (t % tpr) * TP; t /= tpr; y = t % H; b = t / H; }
    const int c0 = blockIdx.z * CPR;

    // ---- staging: fully unrolled, batched loads (8 in flight), then batched LDS writes ----
    const float* wbase = w + ((size_t)o_blk * C + c0) * 9;   // + ol*C*9 + kk
    const int c9 = C * 9;
#pragma unroll
    for (int g0 = 0; g0 < ITERS; g0 += BATCH) {
        float tmp[BATCH];
#pragma unroll
        for (int u = 0; u < BATCH; ++u) {
            int it = g0 + u;
            if (it < ITERS) {
                int idx = tid + it * 256;
                int ol = idx / NK, kk = idx - ol * NK;
                if (idx < NITEMS) tmp[u] = wbase[(size_t)ol * c9 + kk];
            }
        }
#pragma unroll
        for (int u = 0; u < BATCH; ++u) {
            int it = g0 + u;
            if (it < ITERS) {
                int idx = tid + it * 256;
                int ol = idx / NK, kk = idx - ol * NK;
                if (idx < NITEMS) w_s[kk][ol] = tmp[u];
            }
        }
    }
    __syncthreads();

    bool rv[3]; int yoff[3];
#pragma unroll
    for (int dy = 0; dy < 3; ++dy) {
        int yy = y + dy - 1;
        bool v = act && (yy >= 0) && (yy < H);
        rv[dy] = v; yoff[dy] = (v ? yy : 0) * W;
    }
    const bool lok = (x0 > 0), rok = (x0 + TP) < W;
    const int off0 = lok ? -1 : 0;
    const int offT = rok ? TP : (TP - 1);

    float acc[TO][TP] = {};

    for (int cc = 0; cc < CPR; ++cc) {
        const float* xc = x + ((size_t)(b * C + c0 + cc)) * H * W;
#pragma unroll
        for (int dy = 0; dy < 3; ++dy) {
            const float* rp = xc + yoff[dy] + x0;
            float xr[TP + 2];
            if constexpr (TP == 4) {
                float4 v = *(const float4*)rp;          // 16B-aligned: W%4==0, x0%4==0
                xr[1] = rv[dy] ? v.x : 0.f;
                xr[2] = rv[dy] ? v.y : 0.f;
                xr[3] = rv[dy] ? v.z : 0.f;
                xr[4] = rv[dy] ? v.w : 0.f;
                float vl = rp[off0]; xr[0]      = (rv[dy] && lok) ? vl : 0.f;
                float vr = rp[offT]; xr[TP + 1] = (rv[dy] && rok) ? vr : 0.f;
            } else {                                     // TP == 6: x0%2==0 -> 8B-aligned rows
                float2 a0 = *(const float2*)rp;
                float2 a1 = *(const float2*)(rp + 2);
                float2 a2 = *(const float2*)(rp + 4);
                xr[1] = rv[dy] ? a0.x : 0.f;
                xr[2] = rv[dy] ? a0.y : 0.f;
                xr[3] = rv[dy] ? a1.x : 0.f;
                xr[4] = rv[dy] ? a1.y : 0.f;
                xr[5] = rv[dy] ? a2.x : 0.f;
                xr[6] = rv[dy] ? a2.y : 0.f;
                float vl = rp[off0]; xr[0]      = (rv[dy] && lok) ? vl : 0.f;
                float vr = rp[offT]; xr[TP + 1] = (rv[dy] && rok) ? vr : 0.f;
            }
#pragma unroll
            for (int dx = 0; dx < 3; ++dx) {
                const float* wrow = &w_s[cc * 9 + dy * 3 + dx][ty * TO];
                float wv[TO];
                if constexpr (TO == 8) {
                    float4 wa = *(const float4*)wrow;
                    float4 wb = *(const float4*)(wrow + 4);
                    wv[0]=wa.x; wv[1]=wa.y; wv[2]=wa.z; wv[3]=wa.w;
                    wv[4]=wb.x; wv[5]=wb.y; wv[6]=wb.z; wv[7]=wb.w;
                } else if constexpr (TO == 4) {
                    float4 wa = *(const float4*)wrow;    // rows are 16B-aligned (PADOT*4 % 16 == 0)
                    wv[0]=wa.x; wv[1]=wa.y; wv[2]=wa.z; wv[3]=wa.w;
                } else {                                 // TO == 2
                    float2 wa = *(const float2*)wrow;
                    wv[0]=wa.x; wv[1]=wa.y;
                }
#pragma unroll
                for (int i = 0; i < TO; i++)
#pragma unroll
                    for (int p = 0; p < TP; p++) {
                        float d;
                        // exactly 2 VALU: d = x - w; acc += |d| (abs as VOP3 source modifier)
                        asm("v_sub_f32 %1, %2, %3\n\t"
                            "v_add_f32_e64 %0, %0, |%1|"
                            : "+v"(acc[i][p]), "=&v"(d)
                            : "v"(xr[p + dx]), "v"(wv[i]));
                    }
            }
        }
    }
    if (act) {
        float* Pz = P + (size_t)blockIdx.z * ((size_t)2 * O * H * W);
        const int o0 = o_blk + ty * TO;
#pragma unroll
        for (int i = 0; i < TO; i++) {
            float* Tp = Pz + ((size_t)(b * O + (o0 + i)) * H + y) * W + x0;
            if constexpr (TP == 4) {
                *(float4*)Tp = make_float4(-acc[i][0], -acc[i][1], -acc[i][2], -acc[i][3]);
            } else {
                *(float2*)Tp       = make_float2(-acc[i][0], -acc[i][1]);
                *(float2*)(Tp + 2) = make_float2(-acc[i][2], -acc[i][3]);
                *(float2*)(Tp + 4) = make_float2(-acc[i][4], -acc[i][5]);
            }
        }
    }
}

// ---------------- z-reduce P -> T, fused BN sum/sumsq, i4-striped for parallelism -------------
// grid (2*O, S): block (bc, sid) reduces i4 in [sid*len, min(+len, n4)) over all RS z-slices.
// T writes are stripe-exclusive; stats via 2 double atomics per block (dsum pre-zeroed).
__global__ __launch_bounds__(256) void reduce_stats(
    const float* __restrict__ P, float* __restrict__ T, double* __restrict__ dsum,
    int O, int HW, int RS)
{
    __shared__ double sh1[256];
    __shared__ double sh2[256];
    const int bc = blockIdx.x;          // b*O + c
    const int c = bc % O;
    const int n4 = HW >> 2;             // HW % 4 == 0 for all layers
    const int S = gridDim.y;
    const int len = (n4 + S - 1) / S;
    const int i40 = blockIdx.y * len;
    const int i41 = (i40 + len < n4) ? (i40 + len) : n4;
    const size_t outsz4 = (size_t)2 * O * n4;
    const float4* P4 = (const float4*)P + (size_t)bc * n4;
    float4* T4 = (float4*)T + (size_t)bc * n4;
    double a = 0.0, q = 0.0;
    for (int i4 = i40 + threadIdx.x; i4 < i41; i4 += 256) {
        float4 s0 = make_float4(0.f, 0.f, 0.f, 0.f);
        float4 s1 = make_float4(0.f, 0.f, 0.f, 0.f);
        int z = 0;
        for (; z + 1 < RS; z += 2) {
            float4 v0 = P4[(size_t)z * outsz4 + i4];
            float4 v1 = P4[(size_t)(z + 1) * outsz4 + i4];
            s0.x += v0.x; s0.y += v0.y; s0.z += v0.z; s0.w += v0.w;
            s1.x += v1.x; s1.y += v1.y; s1.z += v1.z; s1.w += v1.w;
        }
        if (z < RS) {
            float4 v = P4[(size_t)z * outsz4 + i4];
            s0.x += v.x; s0.y += v.y; s0.z += v.z; s0.w += v.w;
        }
        s0.x += s1.x; s0.y += s1.y; s0.z += s1.z; s0.w += s1.w;
        T4[i4] = s0;
        a += (double)s0.x + (double)s0.y + (double)s0.z + (double)s0.w;
        q += (double)s0.x * s0.x + (double)s0.y * s0.y
           + (double)s0.z * s0.z + (double)s0.w * s0.w;
    }
    sh1[threadIdx.x] = a; sh2[threadIdx.x] = q;
    __syncthreads();
    for (int s = 128; s > 0; s >>= 1) {
        if (threadIdx.x < s) { sh1[threadIdx.x] += sh1[threadIdx.x + s]; sh2[threadIdx.x] += sh2[threadIdx.x + s]; }
        __syncthreads();
    }
    if (threadIdx.x == 0 && sh1[0] == sh1[0]) {   // always true; keeps both sums live
        unsafeAtomicAdd(&dsum[2 * c],     sh1[0]);
        unsafeAtomicAdd(&dsum[2 * c + 1], sh2[0]);
    }
}

__device__ __forceinline__ void bn_coef(const double* __restrict__ dsum,
                                        const float* __restrict__ g,
                                        const float* __restrict__ beta,
                                        int c, int HW, float& sc, float& sh)
{
    double n = 2.0 * (double)HW;
    double mu = dsum[2 * c] / n;
    double var = dsum[2 * c + 1] / n - mu * mu;
    double inv = 1.0 / sqrt(var + (double)BN_EPS);
    double s = (double)g[c] * inv;
    sc = (float)s;
    sh = (float)((double)beta[c] - mu * s);
}

// ---------------- BN apply (inline coef) + feature write + maxpool2 + relu ----------------
__global__ __launch_bounds__(256) void bn_apply_pool(
    const float* __restrict__ T, const double* __restrict__ dsum,
    const float* __restrict__ g, const float* __restrict__ beta,
    float* __restrict__ feat, float* __restrict__ A, int C, int H, int W, int total)
{
    int idx = blockIdx.x * 256 + threadIdx.x;
    if (idx >= total) return;
    int Wh = W >> 1, Hh = H >> 1;
    int px = idx % Wh; int t = idx / Wh;
    int py = t % Hh; t /= Hh;
    int c = t % C; int b = t / C;
    float sc, sh;
    bn_coef(dsum, g, beta, c, H * W, sc, sh);
    size_t base = ((size_t)(b * C + c) * H + 2 * py) * W + 2 * px;
    float f0 = T[base] * sc + sh;
    float f1 = T[base + 1] * sc + sh;
    float f2 = T[base + W] * sc + sh;
    float f3 = T[base + W + 1] * sc + sh;
    feat[base] = f0; feat[base + 1] = f1; feat[base + W] = f2; feat[base + W + 1] = f3;
    A[((size_t)(b * C + c) * Hh + py) * Wh + px] = fmaxf(fmaxf(fmaxf(f0, f1), fmaxf(f2, f3)), 0.f);
}

__global__ __launch_bounds__(256) void bn_apply_np4(
    const float* __restrict__ T, const double* __restrict__ dsum,
    const float* __restrict__ g, const float* __restrict__ beta,
    float* __restrict__ feat, float* __restrict__ A, int C, int HW, int total4)
{
    int idx = blockIdx.x * 256 + threadIdx.x;
    if (idx >= total4) return;
    int e = idx * 4;
    int c = (e / HW) % C;
    float sc, sh;
    bn_coef(dsum, g, beta, c, HW, sc, sh);
    float4 t = *(const float4*)(T + e);
    float4 f = make_float4(t.x * sc + sh, t.y * sc + sh, t.z * sc + sh, t.w * sc + sh);
    *(float4*)(feat + e) = f;
    *(float4*)(A + e) = make_float4(fmaxf(f.x, 0.f), fmaxf(f.y, 0.f), fmaxf(f.z, 0.f), fmaxf(f.w, 0.f));
}

// ---------------- fused global-max(3x3) + final 1x1 adder ----------------
__global__ __launch_bounds__(256) void final_adder(
    const float* __restrict__ A, const float* __restrict__ wl, float* __restrict__ fo)
{
    __shared__ float xs[1024];
    for (int i = threadIdx.x; i < 1024; i += 256) {
        const float* p = A + (size_t)i * 9;
        float m = p[0];
#pragma unroll
        for (int j = 1; j < 9; j++) m = fmaxf(m, p[j]);
        xs[i] = m;                      // i = b*512 + c
    }
    __syncthreads();
    int o = blockIdx.x * 128 + (threadIdx.x >> 1);
    int b = threadIdx.x & 1;
    if (o >= 1000) return;
    const float* wrow = wl + (size_t)o * 512;
    const float* xb = xs + b * 512;
    double s = 0.0;
    for (int c = 0; c < 512; c += 4) {
        float4 wv = *(const float4*)&wrow[c];
        s += (double)fabsf(xb[c] - wv.x) + (double)fabsf(xb[c + 1] - wv.y)
           + (double)fabsf(xb[c + 2] - wv.z) + (double)fabsf(xb[c + 3] - wv.w);
    }
    fo[b * 1000 + o] = (float)(-s);
}

// ---------------- final BN over batch of 2 ----------------
__global__ __launch_bounds__(256) void final_bn(
    const float* __restrict__ fo, const float* __restrict__ gl, const float* __restrict__ bl,
    float* __restrict__ out)
{
    int o = blockIdx.x * 256 + threadIdx.x;
    if (o >= 1000) return;
    float v0 = fo[o], v1 = fo[1000 + o];
    float mu = 0.5f * (v0 + v1);
    float d = v0 - mu;
    float var = d * d;           // mean of squared deviations for n=2
    float iv = rsqrtf(var + (float)BN_EPS);
    float sg = iv * gl[o];
    out[o] = d * sg + bl[o];
    out[1000 + o] = -d * sg + bl[o];
}

extern "C" void kernel_launch(void* const* d_in, const int* in_sizes, int n_in,
                              void* d_out, int out_size, void* d_ws, size_t ws_size,
                              hipStream_t stream)
{
    const float* x = (const float*)d_in[0];
    const float* Wt[8]; const float* Gt[8]; const float* Bt[8];
    for (int i = 0; i < 8; i++) {
        Wt[i] = (const float*)d_in[1 + 3 * i];
        Gt[i] = (const float*)d_in[2 + 3 * i];
        Bt[i] = (const float*)d_in[3 + 3 * i];
    }
    const float* wl = (const float*)d_in[25];
    const float* gl = (const float*)d_in[26];
    const float* bl = (const float*)d_in[27];
    float* out = (float*)d_out;
    float* ws = (float*)d_ws;

    // ws layout (floats): [dsum 11008][T 1179648][A 294912][fo 2000][P 9437184]
    double* dsum = (double*)d_ws;            // 5504 doubles (per-layer BN sum/sumsq)
    float* T  = ws + 11008;
    float* A  = ws + 1190656;
    float* fo = ws + 1485568;
    float* P  = ws + 1487568;
    (void)ws_size;

    hipMemsetAsync(dsum, 0, 5504 * 8, stream);   // re-zeroed every call (graph-replay safe)

    static const int Cc[8]  = {3, 64, 128, 256, 256, 512, 512, 512};
    static const int Oc[8]  = {64, 128, 256, 256, 512, 512, 512, 512};
    static const int Hc[8]  = {96, 48, 24, 24, 12, 12, 6, 6};
    static const int RSc[8] = {1, 16, 32, 32, 64, 64, 128, 128};  // C/RS in {3,4,8}
    static const int TOc[8] = {2, 4, 4, 4, 4, 4, 4, 4};           // R17-proven TO=4 grids
    static const int Sc[8]  = {4, 4, 4, 4, 2, 2, 1, 1};           // reduce_stats i4-stripes
    static const int PLc[8] = {1, 1, 0, 1, 0, 1, 0, 1};
    static const size_t foff[8] = {2000, 1181648, 1771472, 2066384,
                                   2361296, 2508752, 2656208, 2693072};
    static const int doff[8] = {0, 128, 384, 896, 1408, 2432, 3456, 4480};

    const float* cur = x;
    for (int i = 0; i < 8; i++) {
        const int C = Cc[i], O = Oc[i], H = Hc[i], Wd = Hc[i];
        const int HW = H * Wd;
        const int rs = RSc[i];
        const int TP = (i == 0) ? 4 : 6;                      // L2..L8: W in {48,24,12,6}, all %6==0
        const int OT = 16 * TOc[i];
        const int tpr = Wd / TP;
        const int PTt = 2 * H * tpr;
        dim3 grid((PTt + 15) / 16, O / OT, rs);
        if (i == 0)
            adder_partial<4, 2, 3><<<grid, 256, 0, stream>>>(cur, Wt[i], P, C, H, Wd, O);   // CPR=3
        else if (C / rs == 8)
            adder_partial<6, 4, 8><<<grid, 256, 0, stream>>>(cur, Wt[i], P, C, H, Wd, O);   // L4,L6
        else
            adder_partial<6, 4, 4><<<grid, 256, 0, stream>>>(cur, Wt[i], P, C, H, Wd, O);   // L2,3,5,7,8

        double* dsum_l = dsum + doff[i];
        dim3 rgrid(2 * O, Sc[i]);
        reduce_stats<<<rgrid, 256, 0, stream>>>(P, T, dsum_l, O, HW, rs);

        float* feat = out + foff[i];
        if (PLc[i]) {
            int total = 2 * O * (H / 2) * (Wd / 2);
            bn_apply_pool<<<(total + 255) / 256, 256, 0, stream>>>(T, dsum_l, Gt[i], Bt[i], feat, A, O, H, Wd, total);
        } else {
            int total4 = (2 * O * HW) >> 2;
            bn_apply_np4<<<(total4 + 255) / 256, 256, 0, stream>>>(T, dsum_l, Gt[i], Bt[i], feat, A, O, HW, total4);
        }
        cur = A;
    }
    final_adder<<<8, 256, 0, stream>>>(A, wl, fo);   // A = (2,512,3,3) after layer-8 pool+relu
    final_bn<<<4, 256, 0, stream>>>(fo, gl, bl, out);
}